// Round 1
// baseline (244.547 us; speedup 1.0000x reference)
//
#include <hip/hip_runtime.h>
#include <math.h>

// Chamfer distance, fused sweep with packed-fp32 (v_pk_fma_f32) math.
// B=16, N=2048 samp, M=8192 ref, fp32.
//
// v2 changes vs. previous best (100.0 us):
//  - R=4 -> 8 (G=2048, YS=4): halves query-dir reduce incidences + ws1 traffic,
//    better o-tree amortization (min over 8 refs per query), 2x prologue amortization.
//  - prep_kernel deleted: ref transform + query packing folded into sweep;
//    ws1/ws2 init via one hipMemsetAsync(0x7F) (0x7F7F7F7F ~ +inf for uint-ordered
//    atomicMin over non-negative float bit patterns).
//  - ws1p[YS] per-slice array -> single ws1[B][N] with atomicMin (131K atomics,
//    4 contenders/addr); reduce_kernel reads 1 value/query, wave-shuffle reduce
//    instead of 10-level __syncthreads tree.
#define BB 16
#define NN 2048
#define MM 8192

#define BLK 256
#define R 8                    // refs resident per lane
#define G (BLK * R)            // 2048 refs per block
#define YS (MM / G)            // 4 ref slices
#define QCH 32                 // queries per block
#define ZS (NN / QCH)          // 64 query slices
#define QPH 16                 // queries per phase (tqbuf = 16 KB)
#define PHASES (QCH / QPH)     // 2

typedef float v2f __attribute__((ext_vector_type(2)));

static __device__ __forceinline__ v2f v2_splat(float s) { v2f r; r.x = s; r.y = s; return r; }
static __device__ __forceinline__ v2f v2_fma(v2f a, v2f b, v2f c) {
#if __has_builtin(__builtin_elementwise_fma)
    return __builtin_elementwise_fma(a, b, c);   // -> v_pk_fma_f32 on gfx950
#else
    v2f r; r.x = fmaf(a.x, b.x, c.x); r.y = fmaf(a.y, b.y, c.y); return r;
#endif
}

// ws layout (16B-aligned):
//   ws2 : uint[BB*MM]  ref->samp mins  (atomicMin, memset-init 0x7F)   0.5 MB
//   ws1 : uint[BB*NN]  samp->ref mins  (atomicMin, memset-init 0x7F)   128 KB

// grid = (B, YS, ZS) = (16, 4, 64) = 4096 blocks.
// Block: 2048 refs in VGPRs (8/lane, transformed on load); streams 32 queries
// (pairs, packed fp32) in 2 phases of 16. Query-dir partials -> LDS ->
// wave shuffle-min -> atomicMin(ws1). Ref-dir mins -> atomicMin(ws2).
__global__ void __launch_bounds__(BLK, 5) sweep_kernel(const float* __restrict__ ref,
                                                       const float* __restrict__ samp,
                                                       unsigned int* __restrict__ ws2,
                                                       unsigned int* __restrict__ ws1) {
    __shared__ v2f tqbuf[(QPH / 2) * BLK];                 // [pair][tid], 16 KB
    __shared__ float4 qbuf[QCH];                           // QCH/2 pairs x 2 float4, 512 B

    const int b = blockIdx.x;
    const int lane = threadIdx.x & 63;
    const int wv = threadIdx.x >> 6;                       // 0..3
    const int refbase = blockIdx.y * G + wv * (64 * R);
    const int q0 = blockIdx.z * QCH;

    // Stage + transform this block's 32 queries into pair-SoA form:
    // qbuf[2k]   = (x0,x1,y0,y1), qbuf[2k+1] = (z0,z1,w0,w1)
    if (threadIdx.x < QCH / 2) {
        const int k = threadIdx.x;
        const float* s0 = samp + ((size_t)b * NN + q0 + 2 * k) * 3;
        float x0 = s0[0], y0 = s0[1], z0 = s0[2];
        float x1 = s0[3], y1 = s0[4], z1 = s0[5];
        float w0 = fmaf(x0, x0, fmaf(y0, y0, z0 * z0));
        float w1 = fmaf(x1, x1, fmaf(y1, y1, z1 * z1));
        qbuf[2 * k]     = make_float4(x0, x1, y0, y1);
        qbuf[2 * k + 1] = make_float4(z0, z1, w0, w1);
    }

    // Resident refs, transformed on load: (-2x,-2y,-2z,||p||^2)
    const float* rp = ref + ((size_t)b * MM + refbase) * 3;
    float px[R], py[R], pz[R], pp[R], mref[R];
#pragma unroll
    for (int r = 0; r < R; ++r) {
        const float* pq = rp + (size_t)(r * 64 + lane) * 3;
        float p1 = pq[0], p2 = pq[1], p3 = pq[2];
        pp[r] = fmaf(p1, p1, fmaf(p2, p2, p3 * p3));
        px[r] = -2.f * p1; py[r] = -2.f * p2; pz[r] = -2.f * p3;
        mref[r] = INFINITY;
    }
    __syncthreads();

    unsigned int* w1 = ws1 + (size_t)b * NN + q0;

    for (int ph = 0; ph < PHASES; ++ph) {
#pragma unroll 2
        for (int j = 0; j < QPH / 2; ++j) {
            const int jp = ph * (QPH / 2) + j;
            float4 a = qbuf[2 * jp];                       // (x0,x1,y0,y1), LDS broadcast
            float4 c = qbuf[2 * jp + 1];                   // (z0,z1,w0,w1)
            v2f qx; qx.x = a.x; qx.y = a.y;
            v2f qy; qy.x = a.z; qy.y = a.w;
            v2f qz; qz.x = c.x; qz.y = c.y;
            v2f qw; qw.x = c.z; qw.y = c.w;
            v2f t[R];
#pragma unroll
            for (int r = 0; r < R; ++r) {
                v2f s = v2_fma(v2_splat(px[r]), qx, v2_splat(pp[r]));
                s = v2_fma(v2_splat(py[r]), qy, s);
                s = v2_fma(v2_splat(pz[r]), qz, s);
                t[r] = s + qw;                             // full d2 (v_pk_add_f32)
            }
#pragma unroll
            for (int r = 0; r < R; ++r)
                mref[r] = fminf(fminf(mref[r], t[r].x), t[r].y);   // v_min3
            v2f o;
            {
                float a0 = fminf(t[0].x, t[1].x), a1 = fminf(t[2].x, t[3].x);
                float a2 = fminf(t[4].x, t[5].x), a3 = fminf(t[6].x, t[7].x);
                o.x = fminf(fminf(a0, a1), fminf(a2, a3));
                float b0 = fminf(t[0].y, t[1].y), b1 = fminf(t[2].y, t[3].y);
                float b2 = fminf(t[4].y, t[5].y), b3 = fminf(t[6].y, t[7].y);
                o.y = fminf(fminf(b0, b1), fminf(b2, b3));
            }
            tqbuf[j * BLK + threadIdx.x] = o;              // ds_write_b64
        }
        __syncthreads();

        // block-min per query: wave wv reduces pairs jp = wv*2 .. wv*2+1
#pragma unroll
        for (int jj = 0; jj < (QPH / 2) / 4; ++jj) {
            const int jp = wv * ((QPH / 2) / 4) + jj;
            const v2f* s2 = tqbuf + jp * BLK;
            v2f v0 = s2[lane], v1 = s2[lane + 64], v2_ = s2[lane + 128], v3 = s2[lane + 192];
            float m0 = fminf(fminf(v0.x, v1.x), fminf(v2_.x, v3.x));
            float m1 = fminf(fminf(v0.y, v1.y), fminf(v2_.y, v3.y));
#pragma unroll
            for (int s = 32; s > 0; s >>= 1) {
                m0 = fminf(m0, __shfl_xor(m0, s));
                m1 = fminf(m1, __shfl_xor(m1, s));
            }
            if (lane == 0) {
                atomicMin(&w1[ph * QPH + 2 * jp],     __float_as_uint(fmaxf(m0, 0.f)));
                atomicMin(&w1[ph * QPH + 2 * jp + 1], __float_as_uint(fmaxf(m1, 0.f)));
            }
        }
        __syncthreads();
    }

    unsigned int* w2 = ws2 + (size_t)b * MM + refbase;
#pragma unroll
    for (int r = 0; r < R; ++r)
        atomicMin(&w2[r * 64 + lane], __float_as_uint(fmaxf(mref[r], 0.f)));
}

// Final reduce. grid = B, block = 1024. Wave shuffle-reduce + one LDS pass.
#define BLKR 1024
__global__ void __launch_bounds__(BLKR) reduce_kernel(const unsigned int* __restrict__ ws1,
                                                      const unsigned int* __restrict__ ws2,
                                                      float* __restrict__ out) {
    const int b = blockIdx.x;
    const int tid = threadIdx.x;
    const int lane = tid & 63;
    const int wv = tid >> 6;

    float sd1 = 0.f, sr1 = 0.f, sd2 = 0.f, sr2 = 0.f;
#pragma unroll
    for (int i = tid; i < NN; i += BLKR) {
        float v = __uint_as_float(ws1[(size_t)b * NN + i]);  // already >= 0
        sd1 += v;
        sr1 += sqrtf(v);
    }
#pragma unroll
    for (int i = tid; i < MM; i += BLKR) {
        float v = __uint_as_float(ws2[(size_t)b * MM + i]);  // already >= 0
        sd2 += v;
        sr2 += sqrtf(v);
    }
#pragma unroll
    for (int s = 32; s > 0; s >>= 1) {
        sd1 += __shfl_xor(sd1, s);
        sr1 += __shfl_xor(sr1, s);
        sd2 += __shfl_xor(sd2, s);
        sr2 += __shfl_xor(sr2, s);
    }

    __shared__ float4 red[BLKR / 64];
    if (lane == 0) red[wv] = make_float4(sd1, sr1, sd2, sr2);
    __syncthreads();
    if (tid == 0) {
        float4 acc = red[0];
#pragma unroll
        for (int w = 1; w < BLKR / 64; ++w) {
            acc.x += red[w].x; acc.y += red[w].y;
            acc.z += red[w].z; acc.w += red[w].w;
        }
        out[b]      = (acc.y * (1.0f / NN) + acc.w * (1.0f / MM)) * 0.5f;  // cd_p
        out[BB + b] = acc.x * (1.0f / NN) + acc.z * (1.0f / MM);           // cd_t
    }
}

extern "C" void kernel_launch(void* const* d_in, const int* in_sizes, int n_in,
                              void* d_out, int out_size, void* d_ws, size_t ws_size,
                              hipStream_t stream) {
    const float* ref  = (const float*)d_in[0];   // [B, M, 3]
    const float* samp = (const float*)d_in[1];   // [B, N, 3]
    float* out = (float*)d_out;                  // [cd_p[16], cd_t[16]]

    unsigned int* ws2 = (unsigned int*)d_ws;               // BB*MM
    unsigned int* ws1 = ws2 + (size_t)BB * MM;             // BB*NN

    // 0x7F7F7F7F = 3.39e38 as float: acts as +inf for uint-ordered atomicMin
    // over non-negative float bit patterns (all d2 values are far below it).
    hipMemsetAsync(d_ws, 0x7F, ((size_t)BB * MM + (size_t)BB * NN) * sizeof(unsigned int), stream);

    dim3 gs(BB, YS, ZS);   // (16, 4, 64) = 4096 blocks
    sweep_kernel<<<gs, BLK, 0, stream>>>(ref, samp, ws2, ws1);

    reduce_kernel<<<BB, BLKR, 0, stream>>>(ws1, ws2, out);
}

// Round 2
// 106.772 us; speedup vs baseline: 2.2904x; 2.2904x over previous
//
#include <hip/hip_runtime.h>
#include <math.h>

// Chamfer distance, fused sweep with packed-fp32 (v_pk_fma_f32) math.
// B=16, N=2048 samp, M=8192 ref, fp32.
//
// v3 changes vs. v2 (244 us, REGRESSION — scratch spill):
//  - __launch_bounds__(256,5) -> (256,4). HW occupancy steps at VGPR=64/128/256
//    (waves/SIMD 8/4/2); "min 5 waves" is unreachable so the compiler rounded up
//    to 8 waves => 64-VGPR cap => R=8 state (~90 regs) spilled to scratch
//    (FETCH 295MB / WRITE 382MB, VALUBusy 16%). Cap 128 fits the working set.
//  - everything else unchanged from v2: R=8 (G=2048, YS=4), prep fused into
//    sweep, memset(0x7F) init, atomicMin ws1 + wave-shuffle reduce.
#define BB 16
#define NN 2048
#define MM 8192

#define BLK 256
#define R 8                    // refs resident per lane
#define G (BLK * R)            // 2048 refs per block
#define YS (MM / G)            // 4 ref slices
#define QCH 32                 // queries per block
#define ZS (NN / QCH)          // 64 query slices
#define QPH 16                 // queries per phase (tqbuf = 16 KB)
#define PHASES (QCH / QPH)     // 2

typedef float v2f __attribute__((ext_vector_type(2)));

static __device__ __forceinline__ v2f v2_splat(float s) { v2f r; r.x = s; r.y = s; return r; }
static __device__ __forceinline__ v2f v2_fma(v2f a, v2f b, v2f c) {
#if __has_builtin(__builtin_elementwise_fma)
    return __builtin_elementwise_fma(a, b, c);   // -> v_pk_fma_f32 on gfx950
#else
    v2f r; r.x = fmaf(a.x, b.x, c.x); r.y = fmaf(a.y, b.y, c.y); return r;
#endif
}

// ws layout (16B-aligned):
//   ws2 : uint[BB*MM]  ref->samp mins  (atomicMin, memset-init 0x7F)   0.5 MB
//   ws1 : uint[BB*NN]  samp->ref mins  (atomicMin, memset-init 0x7F)   128 KB

// grid = (B, YS, ZS) = (16, 4, 64) = 4096 blocks.
// Block: 2048 refs in VGPRs (8/lane, transformed on load); streams 32 queries
// (pairs, packed fp32) in 2 phases of 16. Query-dir partials -> LDS ->
// wave shuffle-min -> atomicMin(ws1). Ref-dir mins -> atomicMin(ws2).
__global__ void __launch_bounds__(BLK, 4) sweep_kernel(const float* __restrict__ ref,
                                                       const float* __restrict__ samp,
                                                       unsigned int* __restrict__ ws2,
                                                       unsigned int* __restrict__ ws1) {
    __shared__ v2f tqbuf[(QPH / 2) * BLK];                 // [pair][tid], 16 KB
    __shared__ float4 qbuf[QCH];                           // QCH/2 pairs x 2 float4, 512 B

    const int b = blockIdx.x;
    const int lane = threadIdx.x & 63;
    const int wv = threadIdx.x >> 6;                       // 0..3
    const int refbase = blockIdx.y * G + wv * (64 * R);
    const int q0 = blockIdx.z * QCH;

    // Stage + transform this block's 32 queries into pair-SoA form:
    // qbuf[2k]   = (x0,x1,y0,y1), qbuf[2k+1] = (z0,z1,w0,w1)
    if (threadIdx.x < QCH / 2) {
        const int k = threadIdx.x;
        const float* s0 = samp + ((size_t)b * NN + q0 + 2 * k) * 3;
        float x0 = s0[0], y0 = s0[1], z0 = s0[2];
        float x1 = s0[3], y1 = s0[4], z1 = s0[5];
        float w0 = fmaf(x0, x0, fmaf(y0, y0, z0 * z0));
        float w1 = fmaf(x1, x1, fmaf(y1, y1, z1 * z1));
        qbuf[2 * k]     = make_float4(x0, x1, y0, y1);
        qbuf[2 * k + 1] = make_float4(z0, z1, w0, w1);
    }

    // Resident refs, transformed on load: (-2x,-2y,-2z,||p||^2)
    const float* rp = ref + ((size_t)b * MM + refbase) * 3;
    float px[R], py[R], pz[R], pp[R], mref[R];
#pragma unroll
    for (int r = 0; r < R; ++r) {
        const float* pq = rp + (size_t)(r * 64 + lane) * 3;
        float p1 = pq[0], p2 = pq[1], p3 = pq[2];
        pp[r] = fmaf(p1, p1, fmaf(p2, p2, p3 * p3));
        px[r] = -2.f * p1; py[r] = -2.f * p2; pz[r] = -2.f * p3;
        mref[r] = INFINITY;
    }
    __syncthreads();

    unsigned int* w1 = ws1 + (size_t)b * NN + q0;

    for (int ph = 0; ph < PHASES; ++ph) {
#pragma unroll 2
        for (int j = 0; j < QPH / 2; ++j) {
            const int jp = ph * (QPH / 2) + j;
            float4 a = qbuf[2 * jp];                       // (x0,x1,y0,y1), LDS broadcast
            float4 c = qbuf[2 * jp + 1];                   // (z0,z1,w0,w1)
            v2f qx; qx.x = a.x; qx.y = a.y;
            v2f qy; qy.x = a.z; qy.y = a.w;
            v2f qz; qz.x = c.x; qz.y = c.y;
            v2f qw; qw.x = c.z; qw.y = c.w;
            v2f t[R];
#pragma unroll
            for (int r = 0; r < R; ++r) {
                v2f s = v2_fma(v2_splat(px[r]), qx, v2_splat(pp[r]));
                s = v2_fma(v2_splat(py[r]), qy, s);
                s = v2_fma(v2_splat(pz[r]), qz, s);
                t[r] = s + qw;                             // full d2 (v_pk_add_f32)
            }
#pragma unroll
            for (int r = 0; r < R; ++r)
                mref[r] = fminf(fminf(mref[r], t[r].x), t[r].y);   // v_min3
            v2f o;
            {
                float a0 = fminf(t[0].x, t[1].x), a1 = fminf(t[2].x, t[3].x);
                float a2 = fminf(t[4].x, t[5].x), a3 = fminf(t[6].x, t[7].x);
                o.x = fminf(fminf(a0, a1), fminf(a2, a3));
                float b0 = fminf(t[0].y, t[1].y), b1 = fminf(t[2].y, t[3].y);
                float b2 = fminf(t[4].y, t[5].y), b3 = fminf(t[6].y, t[7].y);
                o.y = fminf(fminf(b0, b1), fminf(b2, b3));
            }
            tqbuf[j * BLK + threadIdx.x] = o;              // ds_write_b64
        }
        __syncthreads();

        // block-min per query: wave wv reduces pairs jp = wv*2 .. wv*2+1
#pragma unroll
        for (int jj = 0; jj < (QPH / 2) / 4; ++jj) {
            const int jp = wv * ((QPH / 2) / 4) + jj;
            const v2f* s2 = tqbuf + jp * BLK;
            v2f v0 = s2[lane], v1 = s2[lane + 64], v2_ = s2[lane + 128], v3 = s2[lane + 192];
            float m0 = fminf(fminf(v0.x, v1.x), fminf(v2_.x, v3.x));
            float m1 = fminf(fminf(v0.y, v1.y), fminf(v2_.y, v3.y));
#pragma unroll
            for (int s = 32; s > 0; s >>= 1) {
                m0 = fminf(m0, __shfl_xor(m0, s));
                m1 = fminf(m1, __shfl_xor(m1, s));
            }
            if (lane == 0) {
                atomicMin(&w1[ph * QPH + 2 * jp],     __float_as_uint(fmaxf(m0, 0.f)));
                atomicMin(&w1[ph * QPH + 2 * jp + 1], __float_as_uint(fmaxf(m1, 0.f)));
            }
        }
        __syncthreads();
    }

    unsigned int* w2 = ws2 + (size_t)b * MM + refbase;
#pragma unroll
    for (int r = 0; r < R; ++r)
        atomicMin(&w2[r * 64 + lane], __float_as_uint(fmaxf(mref[r], 0.f)));
}

// Final reduce. grid = B, block = 1024. Wave shuffle-reduce + one LDS pass.
#define BLKR 1024
__global__ void __launch_bounds__(BLKR) reduce_kernel(const unsigned int* __restrict__ ws1,
                                                      const unsigned int* __restrict__ ws2,
                                                      float* __restrict__ out) {
    const int b = blockIdx.x;
    const int tid = threadIdx.x;
    const int lane = tid & 63;
    const int wv = tid >> 6;

    float sd1 = 0.f, sr1 = 0.f, sd2 = 0.f, sr2 = 0.f;
#pragma unroll
    for (int i = tid; i < NN; i += BLKR) {
        float v = __uint_as_float(ws1[(size_t)b * NN + i]);  // already >= 0
        sd1 += v;
        sr1 += sqrtf(v);
    }
#pragma unroll
    for (int i = tid; i < MM; i += BLKR) {
        float v = __uint_as_float(ws2[(size_t)b * MM + i]);  // already >= 0
        sd2 += v;
        sr2 += sqrtf(v);
    }
#pragma unroll
    for (int s = 32; s > 0; s >>= 1) {
        sd1 += __shfl_xor(sd1, s);
        sr1 += __shfl_xor(sr1, s);
        sd2 += __shfl_xor(sd2, s);
        sr2 += __shfl_xor(sr2, s);
    }

    __shared__ float4 red[BLKR / 64];
    if (lane == 0) red[wv] = make_float4(sd1, sr1, sd2, sr2);
    __syncthreads();
    if (tid == 0) {
        float4 acc = red[0];
#pragma unroll
        for (int w = 1; w < BLKR / 64; ++w) {
            acc.x += red[w].x; acc.y += red[w].y;
            acc.z += red[w].z; acc.w += red[w].w;
        }
        out[b]      = (acc.y * (1.0f / NN) + acc.w * (1.0f / MM)) * 0.5f;  // cd_p
        out[BB + b] = acc.x * (1.0f / NN) + acc.z * (1.0f / MM);           // cd_t
    }
}

extern "C" void kernel_launch(void* const* d_in, const int* in_sizes, int n_in,
                              void* d_out, int out_size, void* d_ws, size_t ws_size,
                              hipStream_t stream) {
    const float* ref  = (const float*)d_in[0];   // [B, M, 3]
    const float* samp = (const float*)d_in[1];   // [B, N, 3]
    float* out = (float*)d_out;                  // [cd_p[16], cd_t[16]]

    unsigned int* ws2 = (unsigned int*)d_ws;               // BB*MM
    unsigned int* ws1 = ws2 + (size_t)BB * MM;             // BB*NN

    // 0x7F7F7F7F = 3.39e38 as float: acts as +inf for uint-ordered atomicMin
    // over non-negative float bit patterns (all d2 values are far below it).
    hipMemsetAsync(d_ws, 0x7F, ((size_t)BB * MM + (size_t)BB * NN) * sizeof(unsigned int), stream);

    dim3 gs(BB, YS, ZS);   // (16, 4, 64) = 4096 blocks
    sweep_kernel<<<gs, BLK, 0, stream>>>(ref, samp, ws2, ws1);

    reduce_kernel<<<BB, BLKR, 0, stream>>>(ws1, ws2, out);
}